// Round 1
// baseline (1689.260 us; speedup 1.0000x reference)
//
#include <hip/hip_runtime.h>

#define DIM   33
#define NB    (DIM * DIM * DIM)     // 35937 bins
#define BATCH 8
#define HW    (512 * 512)           // 262144 pixels per image

// ---------------------------------------------------------------------------
// Scatter: each pixel adds 8 trilinear corner weights into cnt (channel 0 of
// the cnt output region) and w*out into the 3 lut channels. Arithmetic is an
// exact replica of the reference (division by binsize, floorf, left-to-right
// products) so bin selection matches bit-for-bit.
// ---------------------------------------------------------------------------
__global__ void tridist_scatter(const float* __restrict__ mask,
                                const float* __restrict__ inp,
                                const float* __restrict__ outp,
                                float* __restrict__ lut,   // [B][3][NB] accumulators
                                float* __restrict__ cnt)   // [B][3][NB]; channel 0 accumulates
{
    int i = blockIdx.x * blockDim.x + threadIdx.x;
    const int total = BATCH * HW;
    if (i >= total) return;

    int b = i / HW;
    int p = i - b * HW;

    float m = mask[(size_t)b * HW + p];
    if (!(m > 0.0f)) return;           // reference multiplies w by m in {0,1}

    const float binsize = 1.000001f / (DIM - 1);

    size_t ibase = (size_t)b * 3 * HW + p;
    float xr = inp[ibase]            / binsize;
    float xg = inp[ibase + HW]       / binsize;
    float xb = inp[ibase + 2 * HW]   / binsize;

    float flr = floorf(xr), flg = floorf(xg), flb = floorf(xb);
    int ir = (int)flr, ig = (int)flg, ib = (int)flb;
    float rd = xr - flr, gd = xg - flg, bd = xb - flb;

    int base = ir + ig * DIM + ib * DIM * DIM;

    float o0 = outp[ibase];
    float o1 = outp[ibase + HW];
    float o2 = outp[ibase + 2 * HW];

    float wr[2] = {1.0f - rd, rd};
    float wg[2] = {1.0f - gd, gd};
    float wb[2] = {1.0f - bd, bd};

    float* lut0 = lut + (size_t)b * 3 * NB;
    float* cnt0 = cnt + (size_t)b * 3 * NB;   // channel 0 slice

    #pragma unroll
    for (int db_ = 0; db_ < 2; ++db_) {
        #pragma unroll
        for (int dg = 0; dg < 2; ++dg) {
            #pragma unroll
            for (int dr = 0; dr < 2; ++dr) {
                float w = (wr[dr] * wg[dg]) * wb[db_];   // left-to-right like ref
                int bin = base + dr + dg * DIM + db_ * DIM * DIM;
                atomicAdd(cnt0 + bin, w);
                atomicAdd(lut0 + bin,            w * o0);
                atomicAdd(lut0 + NB + bin,       w * o1);
                atomicAdd(lut0 + 2 * NB + bin,   w * o2);
            }
        }
    }
}

// ---------------------------------------------------------------------------
// Finalize: lut = cnt>0 ? lut/cnt : 0; broadcast cnt to all 3 channels.
// ---------------------------------------------------------------------------
__global__ void tridist_finalize(float* __restrict__ lut,
                                 float* __restrict__ cnt)
{
    int i = blockIdx.x * blockDim.x + threadIdx.x;
    const int total = BATCH * NB;
    if (i >= total) return;

    int b = i / NB;
    int j = i - b * NB;

    float c = cnt[(size_t)b * 3 * NB + j];    // channel-0 accumulator
    bool nz = (c > 0.0f);

    #pragma unroll
    for (int ch = 0; ch < 3; ++ch) {
        size_t off = ((size_t)b * 3 + ch) * NB + j;
        float v = lut[off];
        lut[off] = nz ? (v / c) : 0.0f;
        cnt[off] = c;
    }
}

// ---------------------------------------------------------------------------
// Passthrough copy of `output` (third tuple element), vectorized float4.
// ---------------------------------------------------------------------------
__global__ void copy_out(const float4* __restrict__ src,
                         float4* __restrict__ dst, int n4)
{
    int i = blockIdx.x * blockDim.x + threadIdx.x;
    int stride = gridDim.x * blockDim.x;
    for (; i < n4; i += stride) dst[i] = src[i];
}

extern "C" void kernel_launch(void* const* d_in, const int* in_sizes, int n_in,
                              void* d_out, int out_size, void* d_ws, size_t ws_size,
                              hipStream_t stream)
{
    const float* mask = (const float*)d_in[0];
    const float* inp  = (const float*)d_in[1];
    const float* outp = (const float*)d_in[2];

    float* out     = (float*)d_out;
    float* lut     = out;                               // B*3*NB
    float* cnt     = out + (size_t)BATCH * 3 * NB;      // B*3*NB
    float* outcopy = out + (size_t)2 * BATCH * 3 * NB;  // B*3*HW

    // Zero the accumulation regions (lut + cnt) every launch.
    hipMemsetAsync(out, 0, (size_t)2 * BATCH * 3 * NB * sizeof(float), stream);

    {
        int total = BATCH * HW;
        int block = 256;
        int grid = (total + block - 1) / block;
        tridist_scatter<<<grid, block, 0, stream>>>(mask, inp, outp, lut, cnt);
    }
    {
        int total = BATCH * NB;
        int block = 256;
        int grid = (total + block - 1) / block;
        tridist_finalize<<<grid, block, 0, stream>>>(lut, cnt);
    }
    {
        int n4 = BATCH * 3 * HW / 4;
        int block = 256;
        int grid = 2048;
        copy_out<<<grid, block, 0, stream>>>((const float4*)outp, (float4*)outcopy, n4);
    }
}

// Round 2
// 264.407 us; speedup vs baseline: 6.3889x; 6.3889x over previous
//
#include <hip/hip_runtime.h>

#define DIM   33
#define NB    (DIM * DIM * DIM)      // 35937
#define BATCH 8
#define HW    (512 * 512)            // 262144
#define SLICE (DIM * DIM)            // 1089 bins per b-slice
#define S     3                      // b-slices per chunk
#define NCH   11                     // chunks; NCH*S == DIM
#define P     8                      // pixel subsets per (batch, chunk)
#define PS    (HW / P)               // 32768 pixels per subset
#define LSZ   (S * SLICE * 4)        // 13068 floats = 52272 B LDS tile

// ---------------------------------------------------------------------------
// LDS-privatized scatter. Each WG owns (batch b, slice-chunk c, pixel subset).
// Accumulates [S][1089][4] (3 lut channels + cnt) in LDS via ds_add_f32,
// then flushes its tile non-atomically to a per-WG replica in d_ws.
// ---------------------------------------------------------------------------
__global__ __launch_bounds__(256) void scatter_lds(const float* __restrict__ mask,
                                                   const float* __restrict__ inp,
                                                   const float* __restrict__ outp,
                                                   float* __restrict__ ws)
{
    __shared__ float acc[LSZ];

    int bid = blockIdx.x;
    int sub = bid % P;
    int c   = (bid / P) % NCH;
    int b   = bid / (P * NCH);
    int lo  = c * S;                 // chunk covers output slices [lo, lo+S)

    for (int i = threadIdx.x; i < LSZ; i += 256) acc[i] = 0.0f;
    __syncthreads();

    const float binsize = 1.000001f / 32.0f;   // matches ref f32 value exactly
    size_t mbase = (size_t)b * HW;
    size_t ibase = (size_t)b * 3 * HW;

    int p0 = sub * PS;
    for (int p = p0 + threadIdx.x; p < p0 + PS; p += 256) {
        float m = mask[mbase + p];
        if (!(m > 0.0f)) continue;

        // Membership test needs only the blue channel.
        float xb = inp[ibase + 2 * HW + p] / binsize;
        float flb = floorf(xb);
        int ib = (int)flb;
        if (ib < lo - 1 || ib > lo + S - 1) continue;   // no corner in chunk
        float bd = xb - flb;

        float xr = inp[ibase + p]      / binsize;
        float xg = inp[ibase + HW + p] / binsize;
        float flr = floorf(xr), flg = floorf(xg);
        int ir = (int)flr, ig = (int)flg;
        float rd = xr - flr, gd = xg - flg;

        float o0 = outp[ibase + p];
        float o1 = outp[ibase + HW + p];
        float o2 = outp[ibase + 2 * HW + p];

        float wr[2]  = {1.0f - rd, rd};
        float wg_[2] = {1.0f - gd, gd};
        float wb[2]  = {1.0f - bd, bd};

        #pragma unroll
        for (int db = 0; db < 2; ++db) {
            int s = ib + db;
            if (s < lo || s >= lo + S) continue;
            int sbase = (s - lo) * SLICE;
            #pragma unroll
            for (int dg = 0; dg < 2; ++dg) {
                #pragma unroll
                for (int dr = 0; dr < 2; ++dr) {
                    float w = (wr[dr] * wg_[dg]) * wb[db];   // ref mul order
                    int l = (sbase + (ir + dr) + (ig + dg) * DIM) * 4;
                    atomicAdd(&acc[l + 0], w * o0);
                    atomicAdd(&acc[l + 1], w * o1);
                    atomicAdd(&acc[l + 2], w * o2);
                    atomicAdd(&acc[l + 3], w);
                }
            }
        }
    }
    __syncthreads();

    // Non-atomic coalesced flush to this WG's replica.
    float* dst = ws + (size_t)bid * LSZ;
    for (int i = threadIdx.x; i < LSZ; i += 256) dst[i] = acc[i];
}

// ---------------------------------------------------------------------------
// Sum the P replicas per (batch, chunk), normalize, write lut + cnt.
// ---------------------------------------------------------------------------
__global__ void reduce_finalize(const float4* __restrict__ ws,
                                float* __restrict__ lut,
                                float* __restrict__ cnt)
{
    int i = blockIdx.x * blockDim.x + threadIdx.x;
    if (i >= BATCH * NB) return;
    int b = i / NB;
    int j = i - b * NB;

    int slice = j / SLICE;
    int rg    = j - slice * SLICE;
    int c     = slice / S;
    int sl    = slice - c * S;

    size_t base4 = ((size_t)(b * NCH + c) * P) * (LSZ / 4) + (size_t)(sl * SLICE + rg);
    float4 sum = {0.f, 0.f, 0.f, 0.f};
    #pragma unroll
    for (int sub = 0; sub < P; ++sub) {
        float4 v = ws[base4 + (size_t)sub * (LSZ / 4)];
        sum.x += v.x; sum.y += v.y; sum.z += v.z; sum.w += v.w;
    }

    float cv = sum.w;
    bool nz = cv > 0.0f;
    size_t o = (size_t)b * 3 * NB + j;
    lut[o]          = nz ? sum.x / cv : 0.0f;
    lut[o + NB]     = nz ? sum.y / cv : 0.0f;
    lut[o + 2 * NB] = nz ? sum.z / cv : 0.0f;
    cnt[o]          = cv;
    cnt[o + NB]     = cv;
    cnt[o + 2 * NB] = cv;
}

// ---------------------------------------------------------------------------
// Fallback path (round-1): global-atomic scatter + finalize. Used only if
// d_ws is too small for the replica buffers.
// ---------------------------------------------------------------------------
__global__ void tridist_scatter(const float* __restrict__ mask,
                                const float* __restrict__ inp,
                                const float* __restrict__ outp,
                                float* __restrict__ lut,
                                float* __restrict__ cnt)
{
    int i = blockIdx.x * blockDim.x + threadIdx.x;
    if (i >= BATCH * HW) return;
    int b = i / HW;
    int p = i - b * HW;

    float m = mask[(size_t)b * HW + p];
    if (!(m > 0.0f)) return;

    const float binsize = 1.000001f / 32.0f;
    size_t ibase = (size_t)b * 3 * HW + p;
    float xr = inp[ibase] / binsize;
    float xg = inp[ibase + HW] / binsize;
    float xb = inp[ibase + 2 * HW] / binsize;
    float flr = floorf(xr), flg = floorf(xg), flb = floorf(xb);
    int ir = (int)flr, ig = (int)flg, ib = (int)flb;
    float rd = xr - flr, gd = xg - flg, bd = xb - flb;
    int base = ir + ig * DIM + ib * DIM * DIM;
    float o0 = outp[ibase], o1 = outp[ibase + HW], o2 = outp[ibase + 2 * HW];
    float wr[2] = {1.0f - rd, rd};
    float wg_[2] = {1.0f - gd, gd};
    float wb[2] = {1.0f - bd, bd};
    float* lut0 = lut + (size_t)b * 3 * NB;
    float* cnt0 = cnt + (size_t)b * 3 * NB;
    #pragma unroll
    for (int db = 0; db < 2; ++db)
        #pragma unroll
        for (int dg = 0; dg < 2; ++dg)
            #pragma unroll
            for (int dr = 0; dr < 2; ++dr) {
                float w = (wr[dr] * wg_[dg]) * wb[db];
                int bin = base + dr + dg * DIM + db * DIM * DIM;
                atomicAdd(cnt0 + bin, w);
                atomicAdd(lut0 + bin, w * o0);
                atomicAdd(lut0 + NB + bin, w * o1);
                atomicAdd(lut0 + 2 * NB + bin, w * o2);
            }
}

__global__ void tridist_finalize(float* __restrict__ lut, float* __restrict__ cnt)
{
    int i = blockIdx.x * blockDim.x + threadIdx.x;
    if (i >= BATCH * NB) return;
    int b = i / NB;
    int j = i - b * NB;
    float c = cnt[(size_t)b * 3 * NB + j];
    bool nz = (c > 0.0f);
    #pragma unroll
    for (int ch = 0; ch < 3; ++ch) {
        size_t off = ((size_t)b * 3 + ch) * NB + j;
        float v = lut[off];
        lut[off] = nz ? (v / c) : 0.0f;
        cnt[off] = c;
    }
}

__global__ void copy_out(const float4* __restrict__ src,
                         float4* __restrict__ dst, int n4)
{
    int i = blockIdx.x * blockDim.x + threadIdx.x;
    int stride = gridDim.x * blockDim.x;
    for (; i < n4; i += stride) dst[i] = src[i];
}

extern "C" void kernel_launch(void* const* d_in, const int* in_sizes, int n_in,
                              void* d_out, int out_size, void* d_ws, size_t ws_size,
                              hipStream_t stream)
{
    const float* mask = (const float*)d_in[0];
    const float* inp  = (const float*)d_in[1];
    const float* outp = (const float*)d_in[2];

    float* out     = (float*)d_out;
    float* lut     = out;                               // [B][3][NB]
    float* cnt     = out + (size_t)BATCH * 3 * NB;      // [B][3][NB]
    float* outcopy = out + (size_t)2 * BATCH * 3 * NB;  // [B][3][HW]

    size_t need = (size_t)BATCH * NCH * P * LSZ * sizeof(float);  // 36.8 MB

    if (ws_size >= need) {
        int nwg = BATCH * NCH * P;   // 704
        scatter_lds<<<nwg, 256, 0, stream>>>(mask, inp, outp, (float*)d_ws);
        int total = BATCH * NB;
        reduce_finalize<<<(total + 255) / 256, 256, 0, stream>>>(
            (const float4*)d_ws, lut, cnt);
    } else {
        hipMemsetAsync(out, 0, (size_t)2 * BATCH * 3 * NB * sizeof(float), stream);
        int total = BATCH * HW;
        tridist_scatter<<<(total + 255) / 256, 256, 0, stream>>>(mask, inp, outp, lut, cnt);
        int totalf = BATCH * NB;
        tridist_finalize<<<(totalf + 255) / 256, 256, 0, stream>>>(lut, cnt);
    }

    {
        int n4 = BATCH * 3 * HW / 4;
        copy_out<<<2048, 256, 0, stream>>>((const float4*)outp, (float4*)outcopy, n4);
    }
}